// Round 9
// baseline (541.412 us; speedup 1.0000x reference)
//
#include <hip/hip_runtime.h>

#define N_NODES 50000
#define N_EDGES 600000
#define DD 128
#define CPB 5                       // chunks (of 64 edges) per block
#define NBLK_AGG 1875               // 1875 * 5 * 64 = 600000 exactly

typedef __attribute__((ext_vector_type(8))) short short8;
typedef __attribute__((ext_vector_type(4))) float f32x4;

__device__ __forceinline__ short f2bf(float f) {
    union { float f; unsigned u; } v; v.f = f;
    unsigned r = v.u + 0x7fffu + ((v.u >> 16) & 1u);
    return (short)(r >> 16);
}
__device__ __forceinline__ float bf2f(short s) {
    union { float f; unsigned u; } v; v.u = ((unsigned)(unsigned short)s) << 16;
    return v.f;
}
__device__ __forceinline__ float u2f(unsigned u) {
    union { float f; unsigned u; } v; v.u = u;
    return v.f;
}

// ---------------------------------------------------------------------------
// Streaming GEMM: Y = X @ W^T + bias -> bf16 (obj_lin). W frag-major in LDS.
// (unchanged from round 8 — proven)
// ---------------------------------------------------------------------------
__global__ __launch_bounds__(256) void k_lin(const float* __restrict__ X,
                                             const float* __restrict__ W,
                                             const float* __restrict__ bias,
                                             short* __restrict__ Y,
                                             int ntiles) {
    __shared__ __align__(16) short Wf[128 * 128];
    for (int i = threadIdx.x; i < 2048; i += 256) {
        const int fl = i & 63, fr = i >> 6;
        const int nt = fr >> 2, ks = fr & 3, fg = fl >> 4, fln = fl & 15;
        const float* s = W + (nt * 16 + fln) * DD + ks * 32 + fg * 8;
        short* d = Wf + i * 8;
#pragma unroll
        for (int j = 0; j < 8; ++j) d[j] = f2bf(s[j]);
    }
    __syncthreads();

    const int wave = threadIdx.x >> 6;
    const int lane = threadIdx.x & 63;
    const int g = lane >> 4, ln = lane & 15;

    float bb[8];
#pragma unroll
    for (int nt = 0; nt < 8; ++nt) bb[nt] = bias[nt * 16 + ln];

    for (int t = blockIdx.x * 4 + wave; t < ntiles; t += gridDim.x * 4) {
        const float* xr = X + (size_t)(t * 16 + ln) * DD;
        short8 a[4];
#pragma unroll
        for (int ks = 0; ks < 4; ++ks) {
            const float* p = xr + ks * 32 + g * 8;
            float4 t0 = *(const float4*)p;
            float4 t1 = *(const float4*)(p + 4);
            short8 v;
            v[0] = f2bf(t0.x); v[1] = f2bf(t0.y); v[2] = f2bf(t0.z); v[3] = f2bf(t0.w);
            v[4] = f2bf(t1.x); v[5] = f2bf(t1.y); v[6] = f2bf(t1.z); v[7] = f2bf(t1.w);
            a[ks] = v;
        }
#pragma unroll
        for (int nt = 0; nt < 8; ++nt) {
            f32x4 acc = {0.f, 0.f, 0.f, 0.f};
#pragma unroll
            for (int ks = 0; ks < 4; ++ks) {
                short8 b = *(const short8*)(Wf + (((nt << 2) + ks) * 64 + lane) * 8);
                acc = __builtin_amdgcn_mfma_f32_16x16x32_bf16(a[ks], b, acc, 0, 0, 0);
            }
#pragma unroll
            for (int r = 0; r < 4; ++r)
                Y[(size_t)(t * 16 + g * 4 + r) * DD + nt * 16 + ln] = f2bf(acc[r] + bb[nt]);
        }
    }
}

// ---------------------------------------------------------------------------
// CSR construction (proven, rounds 2-4): sorted[pos] = {edge id, src}
// ---------------------------------------------------------------------------
__global__ __launch_bounds__(256) void k_zero_int(int* __restrict__ p, int n) {
    int i = blockIdx.x * 256 + threadIdx.x;
    if (i < n) p[i] = 0;
}

__global__ __launch_bounds__(256) void k_count(const int* __restrict__ EI,
                                               int* __restrict__ counts) {
    int e = blockIdx.x * 256 + threadIdx.x;
    if (e < N_EDGES) atomicAdd(&counts[EI[2 * e + 1]], 1);
}

__global__ __launch_bounds__(256) void k_scan1(const int* __restrict__ counts,
                                               int* __restrict__ scanned,
                                               int* __restrict__ bsum) {
    __shared__ int tmp[256];
    const int t = threadIdx.x;
    const int i = blockIdx.x * 256 + t;
    int v = (i < N_NODES) ? counts[i] : 0;
    tmp[t] = v;
    __syncthreads();
#pragma unroll
    for (int off = 1; off < 256; off <<= 1) {
        int x = (t >= off) ? tmp[t - off] : 0;
        __syncthreads();
        tmp[t] += x;
        __syncthreads();
    }
    if (i < N_NODES) scanned[i] = tmp[t] - v;
    if (t == 255) bsum[blockIdx.x] = tmp[255];
}

__global__ __launch_bounds__(256) void k_scan2(int* __restrict__ bsum, int nb) {
    __shared__ int tmp[256];
    const int t = threadIdx.x;
    int v = (t < nb) ? bsum[t] : 0;
    tmp[t] = v;
    __syncthreads();
#pragma unroll
    for (int off = 1; off < 256; off <<= 1) {
        int x = (t >= off) ? tmp[t - off] : 0;
        __syncthreads();
        tmp[t] += x;
        __syncthreads();
    }
    if (t < nb) bsum[t] = tmp[t] - v;
}

__global__ __launch_bounds__(256) void k_scan3(const int* __restrict__ scanned,
                                               const int* __restrict__ bsum,
                                               int* __restrict__ offsets,
                                               int* __restrict__ cursor) {
    int i = blockIdx.x * 256 + threadIdx.x;
    if (i < N_NODES) {
        int off = scanned[i] + bsum[blockIdx.x];
        offsets[i] = off;
        cursor[i] = off;
    }
    if (i == 0) offsets[N_NODES] = N_EDGES;
}

__global__ __launch_bounds__(256) void k_scatter(const int* __restrict__ EI,
                                                 int* __restrict__ cursor,
                                                 int2* __restrict__ sorted) {
    int e = blockIdx.x * 256 + threadIdx.x;
    if (e < N_EDGES) {
        int2 sd = *(const int2*)(EI + 2 * e);
        int pos = atomicAdd(&cursor[sd.y], 1);
        sorted[pos] = make_int2(e, sd.x);       // {edge id, src}
    }
}

// ---------------------------------------------------------------------------
// Fused rel-GEMM + block-level segmented sum over sorted edges.
// Per chunk of 64 edges: 4 waves MFMA 16 gathered rel rows each, stage raw
// msg (bf16-packed, unsigned LDS) -> barrier -> 128 reducer threads (1/col)
// add b_rel + OL[src] + OL[dst], relu, accumulate per segment (block-uniform
// walk), carrying sums across chunks. Interior node: plain store; boundary:
// atomicAdd. out must be pre-zeroed; outer relu in k_relu.
// ---------------------------------------------------------------------------
__global__ __launch_bounds__(256) void k_fagg(const float* __restrict__ RV,
                                              const int2* __restrict__ sorted,
                                              const int* __restrict__ offs,
                                              const float* __restrict__ W,
                                              const float* __restrict__ bias,
                                              const short* __restrict__ OL,
                                              float* __restrict__ out) {
    __shared__ __align__(16) short Wf[128 * 128];
    __shared__ __align__(16) unsigned stg[128 * 33];   // [col][33 words], odd stride
    __shared__ int srcs[64];

    for (int i = threadIdx.x; i < 2048; i += 256) {
        const int fl = i & 63, fr = i >> 6;
        const int nt = fr >> 2, ks = fr & 3, fg = fl >> 4, fln = fl & 15;
        const float* s = W + (nt * 16 + fln) * DD + ks * 32 + fg * 8;
        short* d = Wf + i * 8;
#pragma unroll
        for (int j = 0; j < 8; ++j) d[j] = f2bf(s[j]);
    }
    __syncthreads();

    const int tid = threadIdx.x;
    const int wave = tid >> 6;
    const int lane = tid & 63;
    const int g = lane >> 4, ln = lane & 15;

    const int B0 = blockIdx.x * (CPB * 64);
    const int B1 = B0 + CPB * 64;
    const unsigned short* OLu = (const unsigned short*)OL;

    // reducer state (threads 0..127 own column c = tid); walk is block-uniform
    int d;
    {
        int lo = 0, hi = N_NODES - 1;
        while (lo < hi) {
            int mid = (lo + hi + 1) >> 1;
            if (offs[mid] <= B0) lo = mid; else hi = mid - 1;
        }
        d = lo;                                 // offs[d] <= B0 < offs[d+1]
    }
    int seg_hi = offs[d + 1];
    bool interior = (offs[d] >= B0) && (seg_hi <= B1);
    float acc0 = 0.f, acc1 = 0.f, od = 0.f, bc = 0.f;
    if (tid < 128) {
        od = bf2f((short)OLu[(size_t)d * DD + tid]);
        bc = bias[tid];
    }

    for (int k = 0; k < CPB; ++k) {
        const int c0 = B0 + k * 64;
        const int e0 = c0 + wave * 16;

        // --- GEMM phase (registers + read-only Wf; no stg/srcs touched) ---
        const int2 se = sorted[e0 + ln];        // row ln <- edge e0+ln
        const float* xr = RV + (size_t)se.x * DD;
        short8 a[4];
#pragma unroll
        for (int ks = 0; ks < 4; ++ks) {
            const float* p = xr + ks * 32 + g * 8;
            float4 t0 = *(const float4*)p;
            float4 t1 = *(const float4*)(p + 4);
            short8 v;
            v[0] = f2bf(t0.x); v[1] = f2bf(t0.y); v[2] = f2bf(t0.z); v[3] = f2bf(t0.w);
            v[4] = f2bf(t1.x); v[5] = f2bf(t1.y); v[6] = f2bf(t1.z); v[7] = f2bf(t1.w);
            a[ks] = v;
        }
        f32x4 am[8];
#pragma unroll
        for (int nt = 0; nt < 8; ++nt) {
            am[nt] = (f32x4){0.f, 0.f, 0.f, 0.f};
#pragma unroll
            for (int ks = 0; ks < 4; ++ks) {
                short8 b = *(const short8*)(Wf + (((nt << 2) + ks) * 64 + lane) * 8);
                am[nt] = __builtin_amdgcn_mfma_f32_16x16x32_bf16(a[ks], b, am[nt], 0, 0, 0);
            }
        }

        __syncthreads();   // previous reduce done -> stg/srcs free

        // --- stage phase: msg tile bf16-packed; edge er = wave*16+g*4+r ---
        if (g == 0) srcs[wave * 16 + ln] = se.y;
#pragma unroll
        for (int nt = 0; nt < 8; ++nt) {
            const unsigned lo_ = ((unsigned)(unsigned short)f2bf(am[nt][0])) |
                                 (((unsigned)(unsigned short)f2bf(am[nt][1])) << 16);
            const unsigned hi_ = ((unsigned)(unsigned short)f2bf(am[nt][2])) |
                                 (((unsigned)(unsigned short)f2bf(am[nt][3])) << 16);
            const int c = nt * 16 + ln;
            stg[c * 33 + wave * 8 + g * 2]     = lo_;
            stg[c * 33 + wave * 8 + g * 2 + 1] = hi_;
        }

        __syncthreads();   // stg/srcs ready

        // --- reduce phase: threads 0..127, col c = tid ---
        if (tid < 128) {
            const int c = tid;
#pragma unroll 8
            for (int e = 0; e < 64; ++e) {
                const int ge = c0 + e;
                if (ge == seg_hi) {             // block-uniform flush
                    const float s = acc0 + acc1;
                    if (interior) out[(size_t)d * DD + c] = s;
                    else          atomicAdd(&out[(size_t)d * DD + c], s);
                    acc0 = acc1 = 0.f;
                    do { ++d; } while (offs[d + 1] <= ge);
                    seg_hi = offs[d + 1];
                    interior = (offs[d] >= B0) && (seg_hi <= B1);
                    od = bf2f((short)OLu[(size_t)d * DD + c]);
                }
                const unsigned w = stg[c * 33 + (e >> 1)];
                const float sv = (e & 1) ? u2f(w & 0xffff0000u) : u2f(w << 16);
                const float mv = sv + bc + od +
                                 bf2f((short)OLu[(size_t)srcs[e] * DD + c]);
                if (e & 1) acc1 += fmaxf(mv, 0.f);
                else       acc0 += fmaxf(mv, 0.f);
            }
        }
    }

    // final flush (the in-progress node)
    if (tid < 128) {
        const float s = acc0 + acc1;
        if (interior) out[(size_t)d * DD + tid] = s;
        else          atomicAdd(&out[(size_t)d * DD + tid], s);
    }
}

// ---------------------------------------------------------------------------
// Zero + final ReLU passes over out (proven)
// ---------------------------------------------------------------------------
__global__ __launch_bounds__(256) void k_zerof(float4* __restrict__ p, int n4) {
    int i = blockIdx.x * 256 + threadIdx.x;
    if (i < n4) p[i] = (float4){0.f, 0.f, 0.f, 0.f};
}

__global__ __launch_bounds__(256) void k_relu(float4* __restrict__ p, int n4) {
    int i = blockIdx.x * 256 + threadIdx.x;
    if (i < n4) {
        float4 v = p[i];
        v.x = fmaxf(v.x, 0.f); v.y = fmaxf(v.y, 0.f);
        v.z = fmaxf(v.z, 0.f); v.w = fmaxf(v.w, 0.f);
        p[i] = v;
    }
}

// ---------------------------------------------------------------------------
extern "C" void kernel_launch(void* const* d_in, const int* in_sizes, int n_in,
                              void* d_out, int out_size, void* d_ws, size_t ws_size,
                              hipStream_t stream) {
    const float* obj = (const float*)d_in[0];
    const float* rel = (const float*)d_in[1];
    const int*   ei  = (const int*)d_in[2];
    const float* Wo  = (const float*)d_in[3];
    const float* bo  = (const float*)d_in[4];
    const float* Wr  = (const float*)d_in[5];
    const float* br  = (const float*)d_in[6];
    float* out = (float*)d_out;

    char* ws = (char*)d_ws;
    short* OLb     = (short*)ws;                     // 12,800,000 B
    int2*  sorted  = (int2*)(ws + 12800000);         //  4,800,000 B
    int*   counts  = (int*)(ws + 17600000);
    int*   scanned = (int*)(ws + 17800192);
    int*   offsets = (int*)(ws + 18000896);          // 50001 ints
    int*   cursor  = (int*)(ws + 18201600);
    int*   bsum    = (int*)(ws + 18401792);

    const int NB_E = (N_EDGES + 255) / 256;          // 2344
    const int NB_N = (N_NODES + 255) / 256;          // 196
    const int n4 = N_NODES * DD / 4;                 // 1,600,000

    k_zero_int<<<NB_N, 256, 0, stream>>>(counts, N_NODES);
    k_count<<<NB_E, 256, 0, stream>>>(ei, counts);
    k_scan1<<<NB_N, 256, 0, stream>>>(counts, scanned, bsum);
    k_scan2<<<1, 256, 0, stream>>>(bsum, NB_N);
    k_scan3<<<NB_N, 256, 0, stream>>>(scanned, bsum, offsets, cursor);
    k_scatter<<<NB_E, 256, 0, stream>>>(ei, cursor, sorted);
    k_lin<<<782, 256, 0, stream>>>(obj, Wo, bo, OLb, N_NODES / 16);
    k_zerof<<<(n4 + 255) / 256, 256, 0, stream>>>((float4*)out, n4);
    k_fagg<<<NBLK_AGG, 256, 0, stream>>>(rel, sorted, offsets, Wr, br, OLb, out);
    k_relu<<<(n4 + 255) / 256, 256, 0, stream>>>((float4*)out, n4);
}

// Round 10
// 238.347 us; speedup vs baseline: 2.2715x; 2.2715x over previous
//
#include <hip/hip_runtime.h>

#define N_NODES 50000
#define N_EDGES 600000
#define DD 128

typedef __attribute__((ext_vector_type(8))) short short8;
typedef __attribute__((ext_vector_type(4))) float f32x4;

__device__ __forceinline__ short f2bf(float f) {
    union { float f; unsigned u; } v; v.f = f;
    unsigned r = v.u + 0x7fffu + ((v.u >> 16) & 1u);
    return (short)(r >> 16);
}
__device__ __forceinline__ float bf2f(short s) {
    union { float f; unsigned u; } v; v.u = ((unsigned)(unsigned short)s) << 16;
    return v.f;
}
__device__ __forceinline__ float u2f(unsigned u) {
    union { float f; unsigned u; } v; v.u = u;
    return v.f;
}

// ---------------------------------------------------------------------------
// Streaming GEMM: Y = X @ W^T + bias -> bf16 (obj_lin). W frag-major in LDS.
// (proven)
// ---------------------------------------------------------------------------
__global__ __launch_bounds__(256) void k_lin(const float* __restrict__ X,
                                             const float* __restrict__ W,
                                             const float* __restrict__ bias,
                                             short* __restrict__ Y,
                                             int ntiles) {
    __shared__ __align__(16) short Wf[128 * 128];
    for (int i = threadIdx.x; i < 2048; i += 256) {
        const int fl = i & 63, fr = i >> 6;
        const int nt = fr >> 2, ks = fr & 3, fg = fl >> 4, fln = fl & 15;
        const float* s = W + (nt * 16 + fln) * DD + ks * 32 + fg * 8;
        short* d = Wf + i * 8;
#pragma unroll
        for (int j = 0; j < 8; ++j) d[j] = f2bf(s[j]);
    }
    __syncthreads();

    const int wave = threadIdx.x >> 6;
    const int lane = threadIdx.x & 63;
    const int g = lane >> 4, ln = lane & 15;

    float bb[8];
#pragma unroll
    for (int nt = 0; nt < 8; ++nt) bb[nt] = bias[nt * 16 + ln];

    for (int t = blockIdx.x * 4 + wave; t < ntiles; t += gridDim.x * 4) {
        const float* xr = X + (size_t)(t * 16 + ln) * DD;
        short8 a[4];
#pragma unroll
        for (int ks = 0; ks < 4; ++ks) {
            const float* p = xr + ks * 32 + g * 8;
            float4 t0 = *(const float4*)p;
            float4 t1 = *(const float4*)(p + 4);
            short8 v;
            v[0] = f2bf(t0.x); v[1] = f2bf(t0.y); v[2] = f2bf(t0.z); v[3] = f2bf(t0.w);
            v[4] = f2bf(t1.x); v[5] = f2bf(t1.y); v[6] = f2bf(t1.z); v[7] = f2bf(t1.w);
            a[ks] = v;
        }
#pragma unroll
        for (int nt = 0; nt < 8; ++nt) {
            f32x4 acc = {0.f, 0.f, 0.f, 0.f};
#pragma unroll
            for (int ks = 0; ks < 4; ++ks) {
                short8 b = *(const short8*)(Wf + (((nt << 2) + ks) * 64 + lane) * 8);
                acc = __builtin_amdgcn_mfma_f32_16x16x32_bf16(a[ks], b, acc, 0, 0, 0);
            }
#pragma unroll
            for (int r = 0; r < 4; ++r)
                Y[(size_t)(t * 16 + g * 4 + r) * DD + nt * 16 + ln] = f2bf(acc[r] + bb[nt]);
        }
    }
}

// ---------------------------------------------------------------------------
// CSR-rank construction (counts zeroed by hipMemsetAsync)
// ---------------------------------------------------------------------------
__global__ __launch_bounds__(256) void k_count(const int* __restrict__ EI,
                                               int* __restrict__ counts) {
    int e = blockIdx.x * 256 + threadIdx.x;
    if (e < N_EDGES) atomicAdd(&counts[EI[2 * e + 1]], 1);
}

__global__ __launch_bounds__(256) void k_scan1(const int* __restrict__ counts,
                                               int* __restrict__ scanned,
                                               int* __restrict__ bsum) {
    __shared__ int tmp[256];
    const int t = threadIdx.x;
    const int i = blockIdx.x * 256 + t;
    int v = (i < N_NODES) ? counts[i] : 0;
    tmp[t] = v;
    __syncthreads();
#pragma unroll
    for (int off = 1; off < 256; off <<= 1) {
        int x = (t >= off) ? tmp[t - off] : 0;
        __syncthreads();
        tmp[t] += x;
        __syncthreads();
    }
    if (i < N_NODES) scanned[i] = tmp[t] - v;
    if (t == 255) bsum[blockIdx.x] = tmp[255];
}

// scan3 with the bsum prefix folded in (block reduce over bsum[0..bid))
__global__ __launch_bounds__(256) void k_scan3m(const int* __restrict__ scanned,
                                                const int* __restrict__ bsum,
                                                int* __restrict__ offsets,
                                                int* __restrict__ cursor,
                                                int nb) {
    __shared__ int red[256];
    const int t = threadIdx.x;
    const int bid = blockIdx.x;
    red[t] = (t < bid && t < nb) ? bsum[t] : 0;
    __syncthreads();
#pragma unroll
    for (int off = 128; off > 0; off >>= 1) {
        if (t < off) red[t] += red[t + off];
        __syncthreads();
    }
    const int pre = red[0];
    const int i = bid * 256 + t;
    if (i < N_NODES) {
        const int off = scanned[i] + pre;
        offsets[i] = off;
        cursor[i] = off;
    }
    if (i == 0) offsets[N_NODES] = N_EDGES;
}

__global__ __launch_bounds__(256) void k_scatter2(const int* __restrict__ EI,
                                                  int* __restrict__ cursor,
                                                  int* __restrict__ perm) {
    int e = blockIdx.x * 256 + threadIdx.x;
    if (e < N_EDGES)
        perm[e] = atomicAdd(&cursor[EI[2 * e + 1]], 1);
}

// ---------------------------------------------------------------------------
// Fused rel-GEMM + OL[src] add + scatter-write to dst-sorted position.
// Epilogue col-pair form: thread owns cols (2*lane, 2*lane+1) -> one unsigned
// OL gather + one unsigned Ys store per edge (full 256B row per wave-store).
// ---------------------------------------------------------------------------
__global__ __launch_bounds__(256) void k_fl(const float* __restrict__ RV,
                                            const int* __restrict__ EI,
                                            const int* __restrict__ perm,
                                            const float* __restrict__ W,
                                            const float* __restrict__ bias,
                                            const short* __restrict__ OL,
                                            unsigned* __restrict__ Ysw) {
    __shared__ __align__(16) short Wf[128 * 128];
    __shared__ __align__(16) unsigned stg[4][1160];   // [col][9 words], odd stride

    for (int i = threadIdx.x; i < 2048; i += 256) {
        const int fl = i & 63, fr = i >> 6;
        const int nt = fr >> 2, ks = fr & 3, fg = fl >> 4, fln = fl & 15;
        const float* s = W + (nt * 16 + fln) * DD + ks * 32 + fg * 8;
        short* d = Wf + i * 8;
#pragma unroll
        for (int j = 0; j < 8; ++j) d[j] = f2bf(s[j]);
    }
    __syncthreads();

    const int wave = threadIdx.x >> 6;
    const int lane = threadIdx.x & 63;
    const int g = lane >> 4, ln = lane & 15;
    unsigned* st = stg[wave];

    const float br0 = bias[2 * lane];
    const float br1 = bias[2 * lane + 1];
    const unsigned short* OLu = (const unsigned short*)OL;
    const int NT = N_EDGES / 16;                      // 37500 exact

    for (int t = blockIdx.x * 4 + wave; t < NT; t += gridDim.x * 4) {
        const int e0 = t * 16;

        // A-fragment: row ln <- rel_vecs[e0+ln] (sequential streaming)
        const float* xr = RV + (size_t)(e0 + ln) * DD;
        short8 a[4];
#pragma unroll
        for (int ks = 0; ks < 4; ++ks) {
            const float* p = xr + ks * 32 + g * 8;
            float4 t0 = *(const float4*)p;
            float4 t1 = *(const float4*)(p + 4);
            short8 v;
            v[0] = f2bf(t0.x); v[1] = f2bf(t0.y); v[2] = f2bf(t0.z); v[3] = f2bf(t0.w);
            v[4] = f2bf(t1.x); v[5] = f2bf(t1.y); v[6] = f2bf(t1.z); v[7] = f2bf(t1.w);
            a[ks] = v;
        }

        // src + sorted position for the 16 edges (lanes 0..15 load, shfl later)
        int sp = 0, pp = 0;
        if (lane < 16) {
            sp = EI[2 * (e0 + lane)];
            pp = perm[e0 + lane];
        }

        f32x4 acc[8];
#pragma unroll
        for (int nt = 0; nt < 8; ++nt) {
            acc[nt] = (f32x4){0.f, 0.f, 0.f, 0.f};
#pragma unroll
            for (int ks = 0; ks < 4; ++ks) {
                short8 b = *(const short8*)(Wf + (((nt << 2) + ks) * 64 + lane) * 8);
                acc[nt] = __builtin_amdgcn_mfma_f32_16x16x32_bf16(a[ks], b, acc[nt], 0, 0, 0);
            }
        }

        // stage msg tile bf16-packed: word (e>>1) of col c; rows g*4+r
#pragma unroll
        for (int nt = 0; nt < 8; ++nt) {
            const unsigned lo = ((unsigned)(unsigned short)f2bf(acc[nt][0])) |
                                (((unsigned)(unsigned short)f2bf(acc[nt][1])) << 16);
            const unsigned hi = ((unsigned)(unsigned short)f2bf(acc[nt][2])) |
                                (((unsigned)(unsigned short)f2bf(acc[nt][3])) << 16);
            const int c = nt * 16 + ln;
            st[c * 9 + g * 2]     = lo;
            st[c * 9 + g * 2 + 1] = hi;
        }

        // epilogue: cols (2*lane, 2*lane+1); 1 gather + 1 store per edge
#pragma unroll 8
        for (int e = 0; e < 16; ++e) {
            const int src = __shfl(sp, e);
            const int pos = __shfl(pp, e);
            const unsigned w0 = st[(2 * lane) * 9 + (e >> 1)];
            const unsigned w1 = st[(2 * lane + 1) * 9 + (e >> 1)];
            const float s0 = (e & 1) ? u2f(w0 & 0xffff0000u) : u2f(w0 << 16);
            const float s1 = (e & 1) ? u2f(w1 & 0xffff0000u) : u2f(w1 << 16);
            const unsigned olw = *(const unsigned*)(OLu + (size_t)src * DD + 2 * lane);
            const float y0 = s0 + br0 + u2f(olw << 16);
            const float y1 = s1 + br1 + u2f(olw & 0xffff0000u);
            const unsigned yw = ((unsigned)(unsigned short)f2bf(y0)) |
                                (((unsigned)(unsigned short)f2bf(y1)) << 16);
            Ysw[(size_t)pos * (DD / 2) + lane] = yw;
        }
    }
}

// ---------------------------------------------------------------------------
// Segment sum: one wave per node, sequential Ys rows, col-pair form.
// Writes every node (deg-0 -> 0): subsumes zero + final relu.
// ---------------------------------------------------------------------------
__global__ __launch_bounds__(256) void k_segsum(const unsigned* __restrict__ Ysw,
                                                const short* __restrict__ OL,
                                                const int* __restrict__ offs,
                                                float* __restrict__ out) {
    const int wave = threadIdx.x >> 6;
    const int lane = threadIdx.x & 63;
    const int v = blockIdx.x * 4 + wave;
    if (v >= N_NODES) return;

    const int r0 = offs[v], r1 = offs[v + 1];
    const unsigned short* OLu = (const unsigned short*)OL;
    const unsigned odw = *(const unsigned*)(OLu + (size_t)v * DD + 2 * lane);
    const float od0 = u2f(odw << 16), od1 = u2f(odw & 0xffff0000u);

    float a0 = 0.f, a1 = 0.f;
    int r = r0;
    for (; r + 4 <= r1; r += 4) {
        unsigned y[4];
#pragma unroll
        for (int j = 0; j < 4; ++j)
            y[j] = Ysw[(size_t)(r + j) * (DD / 2) + lane];
#pragma unroll
        for (int j = 0; j < 4; ++j) {
            a0 += fmaxf(u2f(y[j] << 16) + od0, 0.f);
            a1 += fmaxf(u2f(y[j] & 0xffff0000u) + od1, 0.f);
        }
    }
    for (; r < r1; ++r) {
        const unsigned yw = Ysw[(size_t)r * (DD / 2) + lane];
        a0 += fmaxf(u2f(yw << 16) + od0, 0.f);
        a1 += fmaxf(u2f(yw & 0xffff0000u) + od1, 0.f);
    }

    float2 o;
    o.x = fmaxf(a0, 0.f);
    o.y = fmaxf(a1, 0.f);
    *(float2*)(out + (size_t)v * DD + 2 * lane) = o;
}

// ---------------------------------------------------------------------------
extern "C" void kernel_launch(void* const* d_in, const int* in_sizes, int n_in,
                              void* d_out, int out_size, void* d_ws, size_t ws_size,
                              hipStream_t stream) {
    const float* obj = (const float*)d_in[0];
    const float* rel = (const float*)d_in[1];
    const int*   ei  = (const int*)d_in[2];
    const float* Wo  = (const float*)d_in[3];
    const float* bo  = (const float*)d_in[4];
    const float* Wr  = (const float*)d_in[5];
    const float* br  = (const float*)d_in[6];
    float* out = (float*)d_out;

    char* ws = (char*)d_ws;
    unsigned* Ysw  = (unsigned*)ws;                  // 153,600,000 B
    short* OLb     = (short*)(ws + 153600000);       //  12,800,000 B
    int*   perm    = (int*)(ws + 166400000);         //   2,400,000 B
    int*   counts  = (int*)(ws + 168800000);         //     200,000 B
    int*   scanned = (int*)(ws + 169000192);         //     200,704 B
    int*   offsets = (int*)(ws + 169200896);         //     200,704 B (50001 ints)
    int*   cursor  = (int*)(ws + 169401600);         //     200,000 B
    int*   bsum    = (int*)(ws + 169601792);         //       1,024 B

    const int NB_E = (N_EDGES + 255) / 256;          // 2344
    const int NB_N = (N_NODES + 255) / 256;          // 196

    hipMemsetAsync(counts, 0, N_NODES * sizeof(int), stream);
    k_count<<<NB_E, 256, 0, stream>>>(ei, counts);
    k_scan1<<<NB_N, 256, 0, stream>>>(counts, scanned, bsum);
    k_scan3m<<<NB_N, 256, 0, stream>>>(scanned, bsum, offsets, cursor, NB_N);
    k_scatter2<<<NB_E, 256, 0, stream>>>(ei, cursor, perm);
    k_lin<<<782, 256, 0, stream>>>(obj, Wo, bo, OLb, N_NODES / 16);
    k_fl<<<2048, 256, 0, stream>>>(rel, ei, perm, Wr, br, OLb, Ysw);
    k_segsum<<<(N_NODES + 3) / 4, 256, 0, stream>>>(Ysw, OLb, offsets, out);
}

// Round 11
// 238.252 us; speedup vs baseline: 2.2724x; 1.0004x over previous
//
#include <hip/hip_runtime.h>

#define N_NODES 50000
#define N_EDGES 600000
#define DD 128

typedef __attribute__((ext_vector_type(8))) short short8;
typedef __attribute__((ext_vector_type(4))) float f32x4;

__device__ __forceinline__ short f2bf(float f) {
    union { float f; unsigned u; } v; v.f = f;
    unsigned r = v.u + 0x7fffu + ((v.u >> 16) & 1u);
    return (short)(r >> 16);
}
__device__ __forceinline__ float bf2f(short s) {
    union { float f; unsigned u; } v; v.u = ((unsigned)(unsigned short)s) << 16;
    return v.f;
}
__device__ __forceinline__ float u2f(unsigned u) {
    union { float f; unsigned u; } v; v.u = u;
    return v.f;
}
__device__ __forceinline__ unsigned packbf(float a, float b) {
    return ((unsigned)(unsigned short)f2bf(a)) |
           (((unsigned)(unsigned short)f2bf(b)) << 16);
}

// ---------------------------------------------------------------------------
// Streaming GEMM: Y = X @ W^T + bias -> bf16 (obj_lin). W frag-major in LDS.
// X loads non-temporal (read-once stream).
// ---------------------------------------------------------------------------
__global__ __launch_bounds__(256) void k_lin(const float* __restrict__ X,
                                             const float* __restrict__ W,
                                             const float* __restrict__ bias,
                                             short* __restrict__ Y,
                                             int ntiles) {
    __shared__ __align__(16) short Wf[128 * 128];
    for (int i = threadIdx.x; i < 2048; i += 256) {
        const int fl = i & 63, fr = i >> 6;
        const int nt = fr >> 2, ks = fr & 3, fg = fl >> 4, fln = fl & 15;
        const float* s = W + (nt * 16 + fln) * DD + ks * 32 + fg * 8;
        short* d = Wf + i * 8;
#pragma unroll
        for (int j = 0; j < 8; ++j) d[j] = f2bf(s[j]);
    }
    __syncthreads();

    const int wave = threadIdx.x >> 6;
    const int lane = threadIdx.x & 63;
    const int g = lane >> 4, ln = lane & 15;

    float bb[8];
#pragma unroll
    for (int nt = 0; nt < 8; ++nt) bb[nt] = bias[nt * 16 + ln];

    for (int t = blockIdx.x * 4 + wave; t < ntiles; t += gridDim.x * 4) {
        const float* xr = X + (size_t)(t * 16 + ln) * DD;
        short8 a[4];
#pragma unroll
        for (int ks = 0; ks < 4; ++ks) {
            const f32x4* p = (const f32x4*)(xr + ks * 32 + g * 8);
            const f32x4 t0 = __builtin_nontemporal_load(p);
            const f32x4 t1 = __builtin_nontemporal_load(p + 1);
            short8 v;
            v[0] = f2bf(t0[0]); v[1] = f2bf(t0[1]); v[2] = f2bf(t0[2]); v[3] = f2bf(t0[3]);
            v[4] = f2bf(t1[0]); v[5] = f2bf(t1[1]); v[6] = f2bf(t1[2]); v[7] = f2bf(t1[3]);
            a[ks] = v;
        }
#pragma unroll
        for (int nt = 0; nt < 8; ++nt) {
            f32x4 acc = {0.f, 0.f, 0.f, 0.f};
#pragma unroll
            for (int ks = 0; ks < 4; ++ks) {
                short8 b = *(const short8*)(Wf + (((nt << 2) + ks) * 64 + lane) * 8);
                acc = __builtin_amdgcn_mfma_f32_16x16x32_bf16(a[ks], b, acc, 0, 0, 0);
            }
#pragma unroll
            for (int r = 0; r < 4; ++r)
                Y[(size_t)(t * 16 + g * 4 + r) * DD + nt * 16 + ln] = f2bf(acc[r] + bb[nt]);
        }
    }
}

// ---------------------------------------------------------------------------
// CSR-rank construction (counts zeroed by hipMemsetAsync)
// ---------------------------------------------------------------------------
__global__ __launch_bounds__(256) void k_count(const int* __restrict__ EI,
                                               int* __restrict__ counts) {
    int e = blockIdx.x * 256 + threadIdx.x;
    if (e < N_EDGES) atomicAdd(&counts[EI[2 * e + 1]], 1);
}

__global__ __launch_bounds__(256) void k_scan1(const int* __restrict__ counts,
                                               int* __restrict__ scanned,
                                               int* __restrict__ bsum) {
    __shared__ int tmp[256];
    const int t = threadIdx.x;
    const int i = blockIdx.x * 256 + t;
    int v = (i < N_NODES) ? counts[i] : 0;
    tmp[t] = v;
    __syncthreads();
#pragma unroll
    for (int off = 1; off < 256; off <<= 1) {
        int x = (t >= off) ? tmp[t - off] : 0;
        __syncthreads();
        tmp[t] += x;
        __syncthreads();
    }
    if (i < N_NODES) scanned[i] = tmp[t] - v;
    if (t == 255) bsum[blockIdx.x] = tmp[255];
}

__global__ __launch_bounds__(256) void k_scan3m(const int* __restrict__ scanned,
                                                const int* __restrict__ bsum,
                                                int* __restrict__ offsets,
                                                int* __restrict__ cursor,
                                                int nb) {
    __shared__ int red[256];
    const int t = threadIdx.x;
    const int bid = blockIdx.x;
    red[t] = (t < bid && t < nb) ? bsum[t] : 0;
    __syncthreads();
#pragma unroll
    for (int off = 128; off > 0; off >>= 1) {
        if (t < off) red[t] += red[t + off];
        __syncthreads();
    }
    const int pre = red[0];
    const int i = bid * 256 + t;
    if (i < N_NODES) {
        const int off = scanned[i] + pre;
        offsets[i] = off;
        cursor[i] = off;
    }
    if (i == 0) offsets[N_NODES] = N_EDGES;
}

__global__ __launch_bounds__(256) void k_scatter2(const int* __restrict__ EI,
                                                  int* __restrict__ cursor,
                                                  int* __restrict__ perm) {
    int e = blockIdx.x * 256 + threadIdx.x;
    if (e < N_EDGES)
        perm[e] = atomicAdd(&cursor[EI[2 * e + 1]], 1);
}

// ---------------------------------------------------------------------------
// Fused rel-GEMM + OL[src] add + scatter-write to dst-sorted position.
// RV loads non-temporal (don't evict Ys from L3). Stage layout [e2][col],
// stride 136 words: 2-way-free stage writes, paired epilogue reads.
// ---------------------------------------------------------------------------
__global__ __launch_bounds__(256) void k_fl(const float* __restrict__ RV,
                                            const int* __restrict__ EI,
                                            const int* __restrict__ perm,
                                            const float* __restrict__ W,
                                            const float* __restrict__ bias,
                                            const short* __restrict__ OL,
                                            unsigned* __restrict__ Ysw) {
    __shared__ __align__(16) short Wf[128 * 128];
    __shared__ __align__(16) unsigned stg[4][8 * 136];   // [e2][col], stride 136

    for (int i = threadIdx.x; i < 2048; i += 256) {
        const int fl = i & 63, fr = i >> 6;
        const int nt = fr >> 2, ks = fr & 3, fg = fl >> 4, fln = fl & 15;
        const float* s = W + (nt * 16 + fln) * DD + ks * 32 + fg * 8;
        short* d = Wf + i * 8;
#pragma unroll
        for (int j = 0; j < 8; ++j) d[j] = f2bf(s[j]);
    }
    __syncthreads();

    const int wave = threadIdx.x >> 6;
    const int lane = threadIdx.x & 63;
    const int g = lane >> 4, ln = lane & 15;
    unsigned* st = stg[wave];

    const float br0 = bias[2 * lane];
    const float br1 = bias[2 * lane + 1];
    const unsigned short* OLu = (const unsigned short*)OL;
    const int NT = N_EDGES / 16;                      // 37500 exact

    for (int t = blockIdx.x * 4 + wave; t < NT; t += gridDim.x * 4) {
        const int e0 = t * 16;

        // A-fragment: row ln <- rel_vecs[e0+ln] (sequential stream, nt-load)
        const float* xr = RV + (size_t)(e0 + ln) * DD;
        short8 a[4];
#pragma unroll
        for (int ks = 0; ks < 4; ++ks) {
            const f32x4* p = (const f32x4*)(xr + ks * 32 + g * 8);
            const f32x4 t0 = __builtin_nontemporal_load(p);
            const f32x4 t1 = __builtin_nontemporal_load(p + 1);
            short8 v;
            v[0] = f2bf(t0[0]); v[1] = f2bf(t0[1]); v[2] = f2bf(t0[2]); v[3] = f2bf(t0[3]);
            v[4] = f2bf(t1[0]); v[5] = f2bf(t1[1]); v[6] = f2bf(t1[2]); v[7] = f2bf(t1[3]);
            a[ks] = v;
        }

        // src + sorted position for the 16 edges (lanes 0..15 load, shfl later)
        int sp = 0, pp = 0;
        if (lane < 16) {
            sp = EI[2 * (e0 + lane)];
            pp = perm[e0 + lane];
        }

        f32x4 acc[8];
#pragma unroll
        for (int nt = 0; nt < 8; ++nt) {
            acc[nt] = (f32x4){0.f, 0.f, 0.f, 0.f};
#pragma unroll
            for (int ks = 0; ks < 4; ++ks) {
                short8 b = *(const short8*)(Wf + (((nt << 2) + ks) * 64 + lane) * 8);
                acc[nt] = __builtin_amdgcn_mfma_f32_16x16x32_bf16(a[ks], b, acc[nt], 0, 0, 0);
            }
        }

        // stage: row e2 = g*2 + (r>>1); word col = nt*16+ln; lo16=even edge
#pragma unroll
        for (int nt = 0; nt < 8; ++nt) {
            const int c = nt * 16 + ln;
            st[(g * 2) * 136 + c]     = packbf(acc[nt][0], acc[nt][1]);
            st[(g * 2 + 1) * 136 + c] = packbf(acc[nt][2], acc[nt][3]);
        }

        // epilogue: per edge-pair hoisted reads; cols (2*lane, 2*lane+1)
#pragma unroll
        for (int ep = 0; ep < 8; ++ep) {
            const unsigned qx = st[ep * 136 + 2 * lane];
            const unsigned qy = st[ep * 136 + 2 * lane + 1];
#pragma unroll
            for (int sub = 0; sub < 2; ++sub) {
                const int e = 2 * ep + sub;
                const int src = __shfl(sp, e);
                const int pos = __shfl(pp, e);
                const float s0 = sub ? u2f(qx & 0xffff0000u) : u2f(qx << 16);
                const float s1 = sub ? u2f(qy & 0xffff0000u) : u2f(qy << 16);
                const unsigned olw = *(const unsigned*)(OLu + (size_t)src * DD + 2 * lane);
                const float y0 = s0 + br0 + u2f(olw << 16);
                const float y1 = s1 + br1 + u2f(olw & 0xffff0000u);
                Ysw[(size_t)pos * (DD / 2) + lane] = packbf(y0, y1);
            }
        }
    }
}

// ---------------------------------------------------------------------------
// Segment sum: one wave per node; lanes 0-31 even rows, 32-63 odd rows,
// 8B loads (wave = 2 full rows / instruction); shfl_xor(32) finish.
// Writes every node (deg-0 -> 0): subsumes zero + final relu.
// ---------------------------------------------------------------------------
__global__ __launch_bounds__(256) void k_segsum(const unsigned* __restrict__ Ysw,
                                                const short* __restrict__ OL,
                                                const int* __restrict__ offs,
                                                float* __restrict__ out) {
    const int wave = threadIdx.x >> 6;
    const int lane = threadIdx.x & 63;
    const int v = blockIdx.x * 4 + wave;
    if (v >= N_NODES) return;

    const int r0 = offs[v], r1 = offs[v + 1];
    const int half = lane >> 5;
    const int q = lane & 31;
    const unsigned short* OLu = (const unsigned short*)OL;

    const uint2 odw = *(const uint2*)(OLu + (size_t)v * DD + 4 * q);
    const float od0 = u2f(odw.x << 16), od1 = u2f(odw.x & 0xffff0000u);
    const float od2 = u2f(odw.y << 16), od3 = u2f(odw.y & 0xffff0000u);

    float a0 = 0.f, a1 = 0.f, a2 = 0.f, a3 = 0.f;
    for (int r = r0 + half; r < r1; r += 2) {
        const uint2 y = *(const uint2*)(Ysw + (size_t)r * (DD / 2) + 2 * q);
        a0 += fmaxf(u2f(y.x << 16) + od0, 0.f);
        a1 += fmaxf(u2f(y.x & 0xffff0000u) + od1, 0.f);
        a2 += fmaxf(u2f(y.y << 16) + od2, 0.f);
        a3 += fmaxf(u2f(y.y & 0xffff0000u) + od3, 0.f);
    }
    a0 += __shfl_xor(a0, 32);
    a1 += __shfl_xor(a1, 32);
    a2 += __shfl_xor(a2, 32);
    a3 += __shfl_xor(a3, 32);

    if (half == 0) {
        float4 o;
        o.x = fmaxf(a0, 0.f); o.y = fmaxf(a1, 0.f);
        o.z = fmaxf(a2, 0.f); o.w = fmaxf(a3, 0.f);
        *(float4*)(out + (size_t)v * DD + 4 * q) = o;
    }
}

// ---------------------------------------------------------------------------
extern "C" void kernel_launch(void* const* d_in, const int* in_sizes, int n_in,
                              void* d_out, int out_size, void* d_ws, size_t ws_size,
                              hipStream_t stream) {
    const float* obj = (const float*)d_in[0];
    const float* rel = (const float*)d_in[1];
    const int*   ei  = (const int*)d_in[2];
    const float* Wo  = (const float*)d_in[3];
    const float* bo  = (const float*)d_in[4];
    const float* Wr  = (const float*)d_in[5];
    const float* br  = (const float*)d_in[6];
    float* out = (float*)d_out;

    char* ws = (char*)d_ws;
    unsigned* Ysw  = (unsigned*)ws;                  // 153,600,000 B
    short* OLb     = (short*)(ws + 153600000);       //  12,800,000 B
    int*   perm    = (int*)(ws + 166400000);         //   2,400,000 B
    int*   counts  = (int*)(ws + 168800000);         //     200,000 B
    int*   scanned = (int*)(ws + 169000192);         //     200,704 B
    int*   offsets = (int*)(ws + 169200896);         //     200,704 B (50001 ints)
    int*   cursor  = (int*)(ws + 169401600);         //     200,000 B
    int*   bsum    = (int*)(ws + 169601792);         //       1,024 B

    const int NB_E = (N_EDGES + 255) / 256;          // 2344
    const int NB_N = (N_NODES + 255) / 256;          // 196

    hipMemsetAsync(counts, 0, N_NODES * sizeof(int), stream);
    k_count<<<NB_E, 256, 0, stream>>>(ei, counts);
    k_scan1<<<NB_N, 256, 0, stream>>>(counts, scanned, bsum);
    k_scan3m<<<NB_N, 256, 0, stream>>>(scanned, bsum, offsets, cursor, NB_N);
    k_scatter2<<<NB_E, 256, 0, stream>>>(ei, cursor, perm);
    k_lin<<<782, 256, 0, stream>>>(obj, Wo, bo, OLb, N_NODES / 16);
    k_fl<<<2048, 256, 0, stream>>>(rel, ei, perm, Wr, br, OLb, Ysw);
    k_segsum<<<(N_NODES + 3) / 4, 256, 0, stream>>>(Ysw, OLb, offsets, out);
}